// Round 12
// baseline (165.892 us; speedup 1.0000x reference)
//
#include <hip/hip_runtime.h>
#include <cstdint>

// ---------------- problem constants ----------------
#define DD     256
#define HH     1024
#define NNSEQ  4096
#define MT     32            // tokens per block (grid 512 = 2 blocks/CU)
#define XR     46            // MT + 14 halo rows
#define XPITCH 264           // 256 + 8 pad (bf16 elems), row 528 B
#define SLOTP  260           // fp32 slot pitch
#define EPSLN  1e-5f

typedef unsigned short u16;
typedef __attribute__((ext_vector_type(8))) short short8;
typedef __attribute__((ext_vector_type(16))) float f32x16;

// 32x32x16 bf16 MFMA: A,B = short8 (8 bf16), C/D = f32x16.
// A: row=l&31, k=(l>>5)*8+j ; B: col=l&31, k=(l>>5)*8+j
// C/D: col=l&31, row=(reg&3)+8*(reg>>2)+4*(l>>5)   [m74/m101]
#define MFMA32(a, b, c) __builtin_amdgcn_mfma_f32_32x32x16_bf16(a, b, c, 0, 0, 0)

__device__ __forceinline__ u16 f2bf(float f) {           // RNE fp32 -> bf16
  unsigned u = __float_as_uint(f);
  u += 0x7FFF + ((u >> 16) & 1);
  return (u16)(u >> 16);
}
__device__ __forceinline__ float bf2f(u16 s) { return __uint_as_float(((unsigned)s) << 16); }

// tanh-form GELU via sigmoid identity (err ~3e-4, under bf16 quantization).
__device__ __forceinline__ float fast_gelu(float v) {
  const float e = __expf(v * __builtin_fmaf(v * v, -0.0713548163f, -1.5957691216f));
  return v * __builtin_amdgcn_rcpf(1.f + e);
}

// ======== prep: parallel direct pack, 32x32 B-fragment layout (R11) =======
// slab: 32 K-rows x 256 N-cols.  frag fp = g*2+h (g: 32-col group, h: 16-K
// half): dst[fp*512 + l*8 + j] = W[kbase + h*16 + (l>>5)*8 + j][g*32+(l&31)]
__global__ __launch_bounds__(256) void k_prep(
    const float* __restrict__ wmix, const float* __restrict__ wff1,
    const float* __restrict__ wff2, u16* __restrict__ wpk,
    u16* __restrict__ w1pk, u16* __restrict__ w2pk)
{
  const int g = blockIdx.x * 256 + threadIdx.x;
  const int u = g >> 10;                 // slab 0..183
  const int t = g & 1023;                // fragment-of-8 within slab
  const int fp = t >> 6, l = t & 63;
  const int gg = fp >> 1, h = fp & 1;
  const int n = gg * 32 + (l & 31);      // output column
  const int r0 = h * 16 + (l >> 5) * 8;  // first of 8 K-rows (within slab)

  const float* src;
  int rowstride;
  u16* dst;
  if (u < 120) {                                   // conv slab s = u
    src = wmix + (size_t)(u * 32 + r0) * 256 + n;
    rowstride = 256;
    dst = wpk + (size_t)u * 8192;
  } else if (u < 152) {                            // FF1: v = c2*8+s
    const int v = u - 120, c2 = v >> 3, s = v & 7;
    src = wff1 + (size_t)(s * 32 + r0) * 1024 + c2 * 256 + n;
    rowstride = 1024;
    dst = w1pk + (size_t)v * 8192;
  } else {                                         // FF2: v = c2*8+s
    const int v = u - 152, c2 = v >> 3, s = v & 7;
    src = wff2 + (size_t)(c2 * 256 + s * 32 + r0) * 256 + n;
    rowstride = 256;
    dst = w2pk + (size_t)v * 8192;
  }

  float w[8];
#pragma unroll
  for (int j = 0; j < 8; ++j) w[j] = src[(size_t)j * rowstride];

  uint4 pk;
  unsigned* p = (unsigned*)&pk;
#pragma unroll
  for (int jj = 0; jj < 4; ++jj)
    p[jj] = (unsigned)f2bf(w[jj * 2]) | ((unsigned)f2bf(w[jj * 2 + 1]) << 16);
  *(uint4*)&dst[(size_t)fp * 512 + (size_t)l * 8] = pk;
}

// ===== fused: conv(mg K-split) + LN1 + FFN + LN2, MT=32, 2 blocks/CU =====
// R12: 32x32x16 MFMA (zero bank conflicts, 13% better rate — R11 measured)
// PLUS K-parity-split accumulators to restore chain parallelism: conv has
// 4 independent MFMA chains (2 nt x 2 parity), FF1/FF2 have 2 each.  R11's
// regression was dep-latency (1 chain in FFN); fold costs 16 VALU adds.
__global__ __launch_bounds__(512, 4) void k_fused(
    const float* __restrict__ x, const u16* __restrict__ wpk,
    const float* __restrict__ bmix, const float* __restrict__ g1,
    const float* __restrict__ b1, const u16* __restrict__ w1pk,
    const float* __restrict__ bf1, const u16* __restrict__ w2pk,
    const float* __restrict__ bf2, const float* __restrict__ g2,
    const float* __restrict__ b2, float* __restrict__ out)
{
  __shared__ __align__(16) u16 bufA[XR * XPITCH];      // 24.3 KB: xs, then h
  __shared__ __align__(16) u16 asbuf[2 * MT * XPITCH]; // 33.8 KB: slot / 2x gelu
  __shared__ float redS[8][MT], redS2[8][MT];          // 2 KB
  __shared__ float muL[MT], invL[MT];

#define bufB ((float*)asbuf)                       // [MT][SLOTP] conv combine slot

  const int tid = threadIdx.x;
  const int wv = tid >> 6, l = tid & 63;
  const int l31 = l & 31, lh = l >> 5;
  const int mg = wv >> 2, ng = wv & 3;
  const long tok0 = (long)blockIdx.x * MT;
  const int n0 = (int)(tok0 & (NNSEQ - 1));

#define ROWOF(r) (((r) & 3) + 8 * ((r) >> 2) + 4 * lh)

  // ---- acc init: bias in parity-0 chain, zeros in parity-1 chain ----
  f32x16 acc[2][2];
#pragma unroll
  for (int nt = 0; nt < 2; ++nt) {
    const float bm = (mg == 0) ? bmix[ng * 64 + nt * 32 + l31] : 0.f;
#pragma unroll
    for (int r = 0; r < 16; ++r) { acc[nt][0][r] = bm; acc[nt][1][r] = 0.f; }
  }
  const u16* bpkb = wpk + (size_t)(ng * 2048) + (size_t)l * 8;

  // ---- stage x rows [tok0-14, tok0+31] as bf16 ----
  {
    const int cslot = l * 4;
    for (int r = wv; r < XR; r += 8) {
      const int nloc = n0 - 14 + r;
      float4 v = make_float4(0.f, 0.f, 0.f, 0.f);
      if (nloc >= 0) v = *(const float4*)&x[(tok0 - 14 + r) * DD + cslot];
      uint2 pk;
      pk.x = (unsigned)f2bf(v.x) | ((unsigned)f2bf(v.y) << 16);
      pk.y = (unsigned)f2bf(v.z) | ((unsigned)f2bf(v.w) << 16);
      *(uint2*)&bufA[r * XPITCH + cslot] = pk;
    }
  }

  // kg = global 16-K step index [0,240); tap = kg>>4, chan base = (kg&15)*16
#define C_LOAD_A(dst, kg_)                                                      \
  {                                                                             \
    const int tap = (kg_) >> 4, c0 = ((kg_) & 15) * 16;                         \
    dst = *(const short8*)&bufA[(tap + l31) * XPITCH + c0 + lh * 8];            \
  }
#define C_LOAD_B(dst, kg_)                                                      \
  {                                                                             \
    const u16* bp = bpkb + (size_t)((kg_) >> 1) * 8192 + (size_t)((kg_) & 1) * 512; \
    dst[0] = *(const short8*)bp;                                                \
    dst[1] = *(const short8*)(bp + 1024);                                       \
  }

  // ===== conv GEMM: K-half mg (120 x K16 steps), cols ng*64.., 32 rows ===
  // 4 independent chains: acc[nt][u&1].  (kg0 even -> parity of step = u&1.)
  {
    const int kg0 = mg * 120;
    short8 af[4], bfr[4][2];
    C_LOAD_B(bfr[0], kg0 + 0)
    C_LOAD_B(bfr[1], kg0 + 1)
    C_LOAD_B(bfr[2], kg0 + 2)
    C_LOAD_B(bfr[3], kg0 + 3)
    __syncthreads();
    C_LOAD_A(af[0], kg0 + 0)
    C_LOAD_A(af[1], kg0 + 1)
    C_LOAD_A(af[2], kg0 + 2)
    C_LOAD_A(af[3], kg0 + 3)

    for (int sb = 0; sb < 116; sb += 4) {
#pragma unroll
      for (int u = 0; u < 4; ++u) {
        __builtin_amdgcn_s_setprio(1);
        acc[0][u & 1] = MFMA32(af[u], bfr[u][0], acc[0][u & 1]);
        acc[1][u & 1] = MFMA32(af[u], bfr[u][1], acc[1][u & 1]);
        __builtin_amdgcn_s_setprio(0);
        C_LOAD_A(af[u], kg0 + sb + u + 4)
        C_LOAD_B(bfr[u], kg0 + sb + u + 4)
      }
    }
#pragma unroll
    for (int u = 0; u < 4; ++u) {                  // tail: steps 116..119
      __builtin_amdgcn_s_setprio(1);
      acc[0][u & 1] = MFMA32(af[u], bfr[u][0], acc[0][u & 1]);
      acc[1][u & 1] = MFMA32(af[u], bfr[u][1], acc[1][u & 1]);
      __builtin_amdgcn_s_setprio(0);
    }
    // fold parity chains
    acc[0][0] = acc[0][0] + acc[0][1];
    acc[1][0] = acc[1][0] + acc[1][1];
  }
#undef C_LOAD_A
#undef C_LOAD_B

  // ---- x-residual prefetch (mg0) before the slot barrier ----
  float xres[2][16];
  if (mg == 0) {
#pragma unroll
    for (int r = 0; r < 16; ++r) {
      const int row = ROWOF(r);
      const float* xp = &x[(tok0 + row) * DD + ng * 64 + l31];
      xres[0][r] = xp[0];
      xres[1][r] = xp[32];
    }
  }

  // ---- mg1 -> fp32 slot; mg0 combines + residual + LN1 ----
  if (mg == 1) {
#pragma unroll
    for (int nt = 0; nt < 2; ++nt)
#pragma unroll
      for (int r = 0; r < 16; ++r)
        bufB[ROWOF(r) * SLOTP + ng * 64 + nt * 32 + l31] = acc[nt][0][r];
  }
  __syncthreads();

  if (mg == 0) {
    float ps[16], ps2[16];
#pragma unroll
    for (int r = 0; r < 16; ++r) {
      const int row = ROWOF(r);
      float s = 0.f, s2 = 0.f;
#pragma unroll
      for (int nt = 0; nt < 2; ++nt) {
        const int col = ng * 64 + nt * 32 + l31;
        const float y = acc[nt][0][r] + bufB[row * SLOTP + col] + xres[nt][r];
        acc[nt][0][r] = y;
        s += y; s2 += y * y;
      }
#pragma unroll
      for (int off = 1; off < 32; off <<= 1) { s += __shfl_xor(s, off, 64); s2 += __shfl_xor(s2, off, 64); }
      ps[r] = s; ps2[r] = s2;
    }
    if (l31 == 0) {
#pragma unroll
      for (int r = 0; r < 16; ++r) {
        const int row = ROWOF(r);
        redS[ng][row] = ps[r]; redS2[ng][row] = ps2[r];
      }
    }
  }
  __syncthreads();
  if (tid < MT) {
    const float s  = redS[0][tid] + redS[1][tid] + redS[2][tid] + redS[3][tid];
    const float s2 = redS2[0][tid] + redS2[1][tid] + redS2[2][tid] + redS2[3][tid];
    const float mu = s * (1.f / DD);
    const float var = s2 * (1.f / DD) - mu * mu;
    muL[tid] = mu; invL[tid] = rsqrtf(var + EPSLN);
  }
  __syncthreads();

  // s_ = 16-K step [0,16) of chunk c_; slab = c*8 + (s>>1), half = s&1
#define F_LDA(src, dst, s_)                                                     \
    dst = *(const short8*)&src[l31 * XPITCH + (s_) * 16 + lh * 8];
#define F_LDB(wsrc, dst, c_, s_)                                                \
    dst = *(const short8*)(wsrc + (size_t)((c_) * 8 + ((s_) >> 1)) * 8192       \
                          + (size_t)(wv * 2 + ((s_) & 1)) * 512 + (size_t)l * 8);

  // ---- prefetch FF1-B for chunk 0 (hides h-write + barrier) ----
  short8 pb1[3];
  F_LDB(w1pk, pb1[0], 0, 0)
  F_LDB(w1pk, pb1[1], 0, 1)
  F_LDB(w1pk, pb1[2], 0, 2)

  // ---- h (bf16) -> bufA rows 0..31 ----
  if (mg == 0) {
#pragma unroll
    for (int nt = 0; nt < 2; ++nt) {
      const int col = ng * 64 + nt * 32 + l31;
      const float gv = g1[col], bv = b1[col];
#pragma unroll
      for (int r = 0; r < 16; ++r) {
        const int row = ROWOF(r);
        bufA[row * XPITCH + col] = f2bf((acc[nt][0][r] - muL[row]) * invL[row] * gv + bv);
      }
    }
  }
  __syncthreads();

  // ============ FFN: 4 chunks of 256 H-cols; wave tile 32 x 32 ============
  // 2 independent chains per GEMM (K-step parity); acc2 chains persist
  // across chunks and fold once before LN2.
  f32x16 acc2[2];
  {
    const float bv = bf2[wv * 32 + l31];
#pragma unroll
    for (int r = 0; r < 16; ++r) { acc2[0][r] = bv; acc2[1][r] = 0.f; }
  }

  for (int c = 0; c < 4; ++c) {
    u16* asb = asbuf + (c & 1) * (MT * XPITCH);
    // FF1: rows 0..31 x chunk-cols [wv*32,+32), K=256 (16 x K16), depth 3
    f32x16 acc1[2];
    {
      const float bv = bf1[c * 256 + wv * 32 + l31];
#pragma unroll
      for (int r = 0; r < 16; ++r) { acc1[0][r] = bv; acc1[1][r] = 0.f; }
    }
    {
      short8 a3[3], b3[3];
      F_LDA(bufA, a3[0], 0) b3[0] = pb1[0];
      F_LDA(bufA, a3[1], 1) b3[1] = pb1[1];
      F_LDA(bufA, a3[2], 2) b3[2] = pb1[2];
#pragma unroll
      for (int s = 0; s < 13; ++s) {
        const int cur = s % 3;
        __builtin_amdgcn_s_setprio(1);
        acc1[s & 1] = MFMA32(a3[cur], b3[cur], acc1[s & 1]);
        __builtin_amdgcn_s_setprio(0);
        F_LDA(bufA, a3[cur], s + 3)
        F_LDB(w1pk, b3[cur], c, s + 3)
      }
      __builtin_amdgcn_s_setprio(1);
#pragma unroll
      for (int s = 13; s < 16; ++s)
        acc1[s & 1] = MFMA32(a3[s % 3], b3[s % 3], acc1[s & 1]);
      __builtin_amdgcn_s_setprio(0);
    }
    // prefetch FF2-B for this chunk (independent of asb)
    short8 pb2[3];
    F_LDB(w2pk, pb2[0], c, 0)
    F_LDB(w2pk, pb2[1], c, 1)
    F_LDB(w2pk, pb2[2], c, 2)
    // fold FF1 chains + fast gelu -> asb
#pragma unroll
    for (int r = 0; r < 16; ++r) {
      const float g = fast_gelu(acc1[0][r] + acc1[1][r]);
      asb[ROWOF(r) * XPITCH + wv * 32 + l31] = f2bf(g);
    }
    // prefetch next chunk's FF1-B before the barrier
    if (c < 3) {
      F_LDB(w1pk, pb1[0], c + 1, 0)
      F_LDB(w1pk, pb1[1], c + 1, 1)
      F_LDB(w1pk, pb1[2], c + 1, 2)
    }
    __syncthreads();
    // FF2: rows 0..31 x out-cols [wv*32,+32), K = chunk's 256, depth 3
    {
      short8 a3[3], b3[3];
      F_LDA(asb, a3[0], 0) b3[0] = pb2[0];
      F_LDA(asb, a3[1], 1) b3[1] = pb2[1];
      F_LDA(asb, a3[2], 2) b3[2] = pb2[2];
#pragma unroll
      for (int s = 0; s < 13; ++s) {
        const int cur = s % 3;
        __builtin_amdgcn_s_setprio(1);
        acc2[s & 1] = MFMA32(a3[cur], b3[cur], acc2[s & 1]);
        __builtin_amdgcn_s_setprio(0);
        F_LDA(asb, a3[cur], s + 3)
        F_LDB(w2pk, b3[cur], c, s + 3)
      }
      __builtin_amdgcn_s_setprio(1);
#pragma unroll
      for (int s = 13; s < 16; ++s)
        acc2[s & 1] = MFMA32(a3[s % 3], b3[s % 3], acc2[s & 1]);
      __builtin_amdgcn_s_setprio(0);
    }
    // no trailing barrier: next chunk writes the other asb buffer
  }
#undef F_LDA
#undef F_LDB

  // ---- fold FF2 chains, residual (h from bufA) + LN2 ----
  acc2[0] = acc2[0] + acc2[1];
  {
    float ps[16], ps2[16];
    const int col = wv * 32 + l31;
#pragma unroll
    for (int r = 0; r < 16; ++r) {
      const int row = ROWOF(r);
      const float y = acc2[0][r] + bf2f(bufA[row * XPITCH + col]);
      acc2[0][r] = y;
      float s = y, s2 = y * y;
#pragma unroll
      for (int off = 1; off < 32; off <<= 1) { s += __shfl_xor(s, off, 64); s2 += __shfl_xor(s2, off, 64); }
      ps[r] = s; ps2[r] = s2;
    }
    if (l31 == 0) {
#pragma unroll
      for (int r = 0; r < 16; ++r) {
        const int row = ROWOF(r);
        redS[wv][row] = ps[r]; redS2[wv][row] = ps2[r];
      }
    }
  }
  __syncthreads();
  if (tid < MT) {
    float s = 0.f, s2 = 0.f;
#pragma unroll
    for (int k = 0; k < 8; ++k) { s += redS[k][tid]; s2 += redS2[k][tid]; }
    const float mu = s * (1.f / DD);
    const float var = s2 * (1.f / DD) - mu * mu;
    muL[tid] = mu; invL[tid] = rsqrtf(var + EPSLN);
  }
  __syncthreads();

  {
    const int col = wv * 32 + l31;
    const float gv = g2[col], bv = b2[col];
#pragma unroll
    for (int r = 0; r < 16; ++r) {
      const int row = ROWOF(r);
      out[(tok0 + row) * DD + col] = (acc2[0][r] - muL[row]) * invL[row] * gv + bv;
    }
  }
#undef ROWOF
#undef bufB
}

// ---------------- launch ----------------
extern "C" void kernel_launch(void* const* d_in, const int* in_sizes, int n_in,
                              void* d_out, int out_size, void* d_ws, size_t ws_size,
                              hipStream_t stream) {
  const float* x    = (const float*)d_in[0];
  const float* wmix = (const float*)d_in[1];   // [3840][256]
  const float* bmix = (const float*)d_in[2];
  const float* g1   = (const float*)d_in[3];
  const float* b1   = (const float*)d_in[4];
  const float* wff1 = (const float*)d_in[5];   // [256][1024]
  const float* bff1 = (const float*)d_in[6];
  const float* wff2 = (const float*)d_in[7];   // [1024][256]
  const float* bff2 = (const float*)d_in[8];
  const float* g2   = (const float*)d_in[9];
  const float* b2   = (const float*)d_in[10];
  float* out = (float*)d_out;

  u16* wpk  = (u16*)d_ws;                // 120*8192 = 983040 elems (1.97 MB)
  u16* w1pk = wpk + 983040;              // 32*8192 = 262144
  u16* w2pk = w1pk + 262144;             // 262144

  // 184 slabs x 1024 fragments-of-8 = 188416 threads = 736 x 256
  k_prep<<<736, 256, 0, stream>>>(wmix, wff1, wff2, wpk, w1pk, w2pk);

  k_fused<<<512, 512, 0, stream>>>(x, wpk, bmix, g1, b1,
                                   w1pk, bff1, w2pk, bff2, g2, b2, out);
}

// Round 13
// 150.923 us; speedup vs baseline: 1.0992x; 1.0992x over previous
//
#include <hip/hip_runtime.h>
#include <cstdint>

// ---------------- problem constants ----------------
#define DD     256
#define HH     1024
#define NNSEQ  4096
#define MT     32            // tokens per block (grid 512 = 2 blocks/CU)
#define XR     46            // MT + 14 halo rows
#define XPITCH 264           // 256 + 8 pad (bf16 elems), row 528 B
#define SLOTP  260           // fp32 slot pitch
#define EPSLN  1e-5f

typedef unsigned short u16;
typedef __attribute__((ext_vector_type(8))) short short8;
typedef __attribute__((ext_vector_type(4))) float f32x4;

#define MFMA(a, b, c) __builtin_amdgcn_mfma_f32_16x16x32_bf16(a, b, c, 0, 0, 0)

__device__ __forceinline__ u16 f2bf(float f) {           // RNE fp32 -> bf16
  unsigned u = __float_as_uint(f);
  u += 0x7FFF + ((u >> 16) & 1);
  return (u16)(u >> 16);
}
__device__ __forceinline__ float bf2f(u16 s) { return __uint_as_float(((unsigned)s) << 16); }

// tanh-form GELU via sigmoid identity: 0.5v(1+tanh(u)) = v*sigmoid(2u).
// Max |err| vs exact erf-GELU ~3e-4, under the bf16 quantization applied after.
__device__ __forceinline__ float fast_gelu(float v) {
  const float e = __expf(v * __builtin_fmaf(v * v, -0.0713548163f, -1.5957691216f));
  return v * __builtin_amdgcn_rcpf(1.f + e);
}

// ======== prep: fully-parallel direct pack (R8, ~1 us) ====================
// One thread per 8-element output fragment: 184 slabs x 1024 thr.
// dst[fi*512 + l*8 + j] = W[K = s*32 + (l>>4)*8 + j][n = fi*16 + (l&15)]
__global__ __launch_bounds__(256) void k_prep(
    const float* __restrict__ wmix, const float* __restrict__ wff1,
    const float* __restrict__ wff2, u16* __restrict__ wpk,
    u16* __restrict__ w1pk, u16* __restrict__ w2pk)
{
  const int g = blockIdx.x * 256 + threadIdx.x;
  const int u = g >> 10;                 // slab 0..183 (uniform per block)
  const int t = g & 1023;                // fragment within slab
  const int fi = t >> 6, l = t & 63, q = l >> 4, cl = l & 15;
  const int n = fi * 16 + cl;            // output column
  const int r0 = q * 8;                  // first of 8 K-rows

  const float* src;
  int rowstride;
  u16* dst;
  if (u < 120) {                                   // conv slab s = u
    src = wmix + (size_t)(u * 32 + r0) * 256 + n;
    rowstride = 256;
    dst = wpk + (size_t)u * 8192;
  } else if (u < 152) {                            // FF1: u' = c2*8+s
    const int v = u - 120, c2 = v >> 3, s = v & 7;
    src = wff1 + (size_t)(s * 32 + r0) * 1024 + c2 * 256 + n;
    rowstride = 1024;
    dst = w1pk + (size_t)v * 8192;
  } else {                                         // FF2: u' = c2*8+s
    const int v = u - 152, c2 = v >> 3, s = v & 7;
    src = wff2 + (size_t)(c2 * 256 + s * 32 + r0) * 256 + n;
    rowstride = 256;
    dst = w2pk + (size_t)v * 8192;
  }

  float w[8];
#pragma unroll
  for (int j = 0; j < 8; ++j) w[j] = src[(size_t)j * rowstride];

  uint4 pk;
  unsigned* p = (unsigned*)&pk;
#pragma unroll
  for (int jj = 0; jj < 4; ++jj)
    p[jj] = (unsigned)f2bf(w[jj * 2]) | ((unsigned)f2bf(w[jj * 2 + 1]) << 16);
  *(uint4*)&dst[(size_t)fi * 512 + (size_t)l * 8] = pk;
}

// ===== fused: conv(mg K-split) + LN1 + FFN + LN2, MT=32, 2 blocks/CU =====
// CHAMPION (R10, k_fused 74.9 us): R4 structure + latency/arbitration pass.
//  - depth-3 conv pipeline, B-issue hoisted above the staging barrier
//  - FF1/FF2 depth-2 A/B double-buffer, peeled tails
//  - s_setprio(1) around MFMA bursts (2 independent blocks/CU)
//  - x-residual prefetch before the slot barrier
//  - cross-phase weight prefetch (FF2-B before gelu; next-chunk FF1-B
//    before the chunk barrier; chunk-0 FF1-B before h-write barrier)
// R11/R12 (32x32x16 MFMA +/- split accumulators) both regressed: 1-2 acc
// chains are dep-latency-bound, and extra f32x16 chains spill at 64 VGPR.
// 16x16x32 with 8 independent acc chains is the right shape here.
__global__ __launch_bounds__(512, 4) void k_fused(
    const float* __restrict__ x, const u16* __restrict__ wpk,
    const float* __restrict__ bmix, const float* __restrict__ g1,
    const float* __restrict__ b1, const u16* __restrict__ w1pk,
    const float* __restrict__ bf1, const u16* __restrict__ w2pk,
    const float* __restrict__ bf2, const float* __restrict__ g2,
    const float* __restrict__ b2, float* __restrict__ out)
{
  __shared__ __align__(16) u16 bufA[XR * XPITCH];      // 24.3 KB: xs, then h rows 0..31
  __shared__ __align__(16) u16 asbuf[2 * MT * XPITCH]; // 33.8 KB: fp32 slot / 2x gelu buf
  __shared__ float redS[8][MT], redS2[8][MT];          // 2 KB
  __shared__ float muL[MT], invL[MT];

#define bufB ((float*)asbuf)                       // [MT][SLOTP] conv combine slot

  const int tid = threadIdx.x;
  const int wv = tid >> 6, l = tid & 63, q = l >> 4, cl = l & 15;
  const int mg = wv >> 2, ng = wv & 3;
  const long tok0 = (long)blockIdx.x * MT;
  const int n0 = (int)(tok0 & (NNSEQ - 1));

  // ---- acc init + base pointers hoisted above staging (overlaps) ----
  f32x4 acc[2][4];
#pragma unroll
  for (int nt = 0; nt < 4; ++nt) {
    const float bm = (mg == 0) ? bmix[ng * 64 + nt * 16 + cl] : 0.f;
#pragma unroll
    for (int mt = 0; mt < 2; ++mt) acc[mt][nt] = (f32x4){bm, bm, bm, bm};
  }
  const u16* bbase = wpk + (size_t)(mg * 60) * 8192 + (size_t)(ng * 4) * 512 + (size_t)l * 8;

  // ---- stage x rows [tok0-14, tok0+31] as bf16 ----
  {
    const int cslot = l * 4;
    for (int r = wv; r < XR; r += 8) {
      const int nloc = n0 - 14 + r;
      float4 v = make_float4(0.f, 0.f, 0.f, 0.f);
      if (nloc >= 0) v = *(const float4*)&x[(tok0 - 14 + r) * DD + cslot];
      uint2 pk;
      pk.x = (unsigned)f2bf(v.x) | ((unsigned)f2bf(v.y) << 16);
      pk.y = (unsigned)f2bf(v.z) | ((unsigned)f2bf(v.w) << 16);
      *(uint2*)&bufA[r * XPITCH + cslot] = pk;
    }
  }

#define LOAD_A(dst, s_)                                                         \
  {                                                                             \
    const int ks = mg * 60 + (s_);                                              \
    const int xrow = ks >> 3, c0 = (ks & 7) * 32;                               \
    _Pragma("unroll")                                                           \
    for (int mt = 0; mt < 2; ++mt)                                              \
      dst[mt] = *(const short8*)&bufA[(xrow + mt * 16 + cl) * XPITCH + c0 + q * 8]; \
  }
#define LOAD_B(dst, s_)                                                         \
  {                                                                             \
    const u16* bp = bbase + (size_t)(s_) * 8192;                                \
    _Pragma("unroll")                                                           \
    for (int nt = 0; nt < 4; ++nt)                                              \
      dst[nt] = *(const short8*)(bp + nt * 512);                                \
  }

  // ================= conv GEMM: K-half mg, cols ng*64.., 32 rows ========
  // Depth-3 pipeline; B (global) for steps 0..2 issued BEFORE the barrier
  // so the L2 latency hides under staging + barrier wait.
  {
    short8 af[3][2], bfr[3][4];
    LOAD_B(bfr[0], 0)
    LOAD_B(bfr[1], 1)
    LOAD_B(bfr[2], 2)
    __syncthreads();
    LOAD_A(af[0], 0)
    LOAD_A(af[1], 1)
    LOAD_A(af[2], 2)

    for (int sb = 0; sb < 57; sb += 3) {
#pragma unroll
      for (int u = 0; u < 3; ++u) {
        __builtin_amdgcn_s_setprio(1);
#pragma unroll
        for (int mt = 0; mt < 2; ++mt)
#pragma unroll
          for (int nt = 0; nt < 4; ++nt)
            acc[mt][nt] = MFMA(af[u][mt], bfr[u][nt], acc[mt][nt]);
        __builtin_amdgcn_s_setprio(0);
        LOAD_A(af[u], sb + u + 3)
        LOAD_B(bfr[u], sb + u + 3)
      }
    }
#pragma unroll
    for (int u = 0; u < 3; ++u) {                  // tail: steps 57..59
      __builtin_amdgcn_s_setprio(1);
#pragma unroll
      for (int mt = 0; mt < 2; ++mt)
#pragma unroll
        for (int nt = 0; nt < 4; ++nt)
          acc[mt][nt] = MFMA(af[u][mt], bfr[u][nt], acc[mt][nt]);
      __builtin_amdgcn_s_setprio(0);
    }
  }
#undef LOAD_A
#undef LOAD_B

  // ---- x-residual prefetch (mg0): issue BEFORE the slot barrier so the
  // ~200cy L2 latency hides under mg1's slot stores + barrier wait ----
  float xres[2][4][4];
  if (mg == 0) {
#pragma unroll
    for (int mt = 0; mt < 2; ++mt)
#pragma unroll
      for (int reg = 0; reg < 4; ++reg) {
        const int row = mt * 16 + q * 4 + reg;
        const float* xp = &x[(tok0 + row) * DD + ng * 64 + cl];
#pragma unroll
        for (int nt = 0; nt < 4; ++nt) xres[mt][reg][nt] = xp[nt * 16];
      }
  }

  // ---- mg1 -> fp32 slot; mg0 combines + residual + LN1 ----
  if (mg == 1) {
#pragma unroll
    for (int mt = 0; mt < 2; ++mt)
#pragma unroll
      for (int nt = 0; nt < 4; ++nt)
#pragma unroll
        for (int reg = 0; reg < 4; ++reg)
          bufB[(mt * 16 + q * 4 + reg) * SLOTP + ng * 64 + nt * 16 + cl] = acc[mt][nt][reg];
  }
  __syncthreads();

  if (mg == 0) {
    float ps[2][4], ps2[2][4];
#pragma unroll
    for (int mt = 0; mt < 2; ++mt)
#pragma unroll
      for (int reg = 0; reg < 4; ++reg) {
        const int row = mt * 16 + q * 4 + reg;
        float s = 0.f, s2 = 0.f;
#pragma unroll
        for (int nt = 0; nt < 4; ++nt) {
          const int col = ng * 64 + nt * 16 + cl;
          const float y = acc[mt][nt][reg] + bufB[row * SLOTP + col]
                        + xres[mt][reg][nt];                 // fp32 residual
          acc[mt][nt][reg] = y;
          s += y; s2 += y * y;
        }
#pragma unroll
        for (int off = 1; off < 16; off <<= 1) { s += __shfl_xor(s, off, 64); s2 += __shfl_xor(s2, off, 64); }
        ps[mt][reg] = s; ps2[mt][reg] = s2;
      }
    if (cl == 0) {
#pragma unroll
      for (int mt = 0; mt < 2; ++mt)
#pragma unroll
        for (int reg = 0; reg < 4; ++reg) {
          const int row = mt * 16 + q * 4 + reg;
          redS[ng][row] = ps[mt][reg]; redS2[ng][row] = ps2[mt][reg];
        }
    }
  }
  __syncthreads();
  if (tid < MT) {
    const float s  = redS[0][tid] + redS[1][tid] + redS[2][tid] + redS[3][tid];
    const float s2 = redS2[0][tid] + redS2[1][tid] + redS2[2][tid] + redS2[3][tid];
    const float mu = s * (1.f / DD);
    const float var = s2 * (1.f / DD) - mu * mu;
    muL[tid] = mu; invL[tid] = rsqrtf(var + EPSLN);
  }
  __syncthreads();

#define FF_LDB(wsrc, dst, c_, s_)                                               \
  {                                                                             \
    const u16* bp = wsrc + (size_t)((c_) * 8 + (s_)) * 8192 + (size_t)(wv * 2) * 512 + (size_t)l * 8; \
    _Pragma("unroll")                                                           \
    for (int nt = 0; nt < 2; ++nt)                                              \
      dst[nt] = *(const short8*)(bp + nt * 512);                                \
  }
#define FF_LDA(src, dst, s_)                                                    \
  {                                                                             \
    _Pragma("unroll")                                                           \
    for (int mt = 0; mt < 2; ++mt)                                              \
      dst[mt] = *(const short8*)&src[(mt * 16 + cl) * XPITCH + (s_) * 32 + q * 8]; \
  }

  // ---- prefetch FF1-B for chunk 0 (hides h-write + barrier) ----
  short8 pb1[2][2];
  FF_LDB(w1pk, pb1[0], 0, 0)
  FF_LDB(w1pk, pb1[1], 0, 1)

  // ---- h (bf16) -> bufA rows 0..31 ----
  if (mg == 0) {
#pragma unroll
    for (int nt = 0; nt < 4; ++nt) {
      const int col = ng * 64 + nt * 16 + cl;
      const float gv = g1[col], bv = b1[col];
#pragma unroll
      for (int mt = 0; mt < 2; ++mt)
#pragma unroll
        for (int reg = 0; reg < 4; ++reg) {
          const int row = mt * 16 + q * 4 + reg;
          const float hv = (acc[mt][nt][reg] - muL[row]) * invL[row] * gv + bv;
          bufA[row * XPITCH + col] = f2bf(hv);
        }
    }
  }
  __syncthreads();

  // ============ FFN: 4 chunks of 256 H-cols; wave tile 32 x 32 ============
  // asb double-buffered by chunk parity (one barrier per chunk).  Weight
  // prefetch decoupled from barriers: FF2-B issued before gelu+barrier,
  // next chunk's FF1-B issued before the barrier too.
  f32x4 acc2[2][2];
#pragma unroll
  for (int nt = 0; nt < 2; ++nt) {
    const float bv = bf2[wv * 32 + nt * 16 + cl];
#pragma unroll
    for (int mt = 0; mt < 2; ++mt) acc2[mt][nt] = (f32x4){bv, bv, bv, bv};
  }

  for (int c = 0; c < 4; ++c) {
    u16* asb = asbuf + (c & 1) * (MT * XPITCH);
    // FF1: rows 0..31 (mt) x chunk-cols [wv*32,+32), K = 256
    f32x4 acc1[2][2];
#pragma unroll
    for (int nt = 0; nt < 2; ++nt) {
      const float bv = bf1[c * 256 + wv * 32 + nt * 16 + cl];
#pragma unroll
      for (int mt = 0; mt < 2; ++mt) acc1[mt][nt] = (f32x4){bv, bv, bv, bv};
    }
    {
      short8 a2[2][2], b2r[2][2];
      FF_LDA(bufA, a2[0], 0)
      b2r[0][0] = pb1[0][0]; b2r[0][1] = pb1[0][1];
      FF_LDA(bufA, a2[1], 1)
      b2r[1][0] = pb1[1][0]; b2r[1][1] = pb1[1][1];
#pragma unroll
      for (int s = 0; s < 6; ++s) {
        const int cur = s & 1;
        __builtin_amdgcn_s_setprio(1);
#pragma unroll
        for (int mt = 0; mt < 2; ++mt)
#pragma unroll
          for (int nt = 0; nt < 2; ++nt)
            acc1[mt][nt] = MFMA(a2[cur][mt], b2r[cur][nt], acc1[mt][nt]);
        __builtin_amdgcn_s_setprio(0);
        FF_LDA(bufA, a2[cur], s + 2) FF_LDB(w1pk, b2r[cur], c, s + 2)
      }
      __builtin_amdgcn_s_setprio(1);
#pragma unroll
      for (int s = 6; s < 8; ++s) {
        const int cur = s & 1;
#pragma unroll
        for (int mt = 0; mt < 2; ++mt)
#pragma unroll
          for (int nt = 0; nt < 2; ++nt)
            acc1[mt][nt] = MFMA(a2[cur][mt], b2r[cur][nt], acc1[mt][nt]);
      }
      __builtin_amdgcn_s_setprio(0);
    }
    // prefetch FF2-B for this chunk (independent of asb -> hides gelu +
    // barrier + L2 latency)
    short8 pb2[2][2];
    FF_LDB(w2pk, pb2[0], c, 0)
    FF_LDB(w2pk, pb2[1], c, 1)
    // fast gelu -> asb (A-layout, chunk-local cols wv*32+nt*16+cl)
#pragma unroll
    for (int mt = 0; mt < 2; ++mt)
#pragma unroll
      for (int nt = 0; nt < 2; ++nt)
#pragma unroll
        for (int reg = 0; reg < 4; ++reg) {
          const float g = fast_gelu(acc1[mt][nt][reg]);
          asb[(mt * 16 + q * 4 + reg) * XPITCH + wv * 32 + nt * 16 + cl] = f2bf(g);
        }
    // prefetch next chunk's FF1-B before the barrier
    if (c < 3) {
      FF_LDB(w1pk, pb1[0], c + 1, 0)
      FF_LDB(w1pk, pb1[1], c + 1, 1)
    }
    __syncthreads();
    // FF2: rows 0..31 x out-cols [wv*32,+32), K = chunk's 256
    {
      short8 a2[2][2], b2r[2][2];
      FF_LDA(asb, a2[0], 0)
      b2r[0][0] = pb2[0][0]; b2r[0][1] = pb2[0][1];
      FF_LDA(asb, a2[1], 1)
      b2r[1][0] = pb2[1][0]; b2r[1][1] = pb2[1][1];
#pragma unroll
      for (int s = 0; s < 6; ++s) {
        const int cur = s & 1;
        __builtin_amdgcn_s_setprio(1);
#pragma unroll
        for (int mt = 0; mt < 2; ++mt)
#pragma unroll
          for (int nt = 0; nt < 2; ++nt)
            acc2[mt][nt] = MFMA(a2[cur][mt], b2r[cur][nt], acc2[mt][nt]);
        __builtin_amdgcn_s_setprio(0);
        FF_LDA(asb, a2[cur], s + 2) FF_LDB(w2pk, b2r[cur], c, s + 2)
      }
      __builtin_amdgcn_s_setprio(1);
#pragma unroll
      for (int s = 6; s < 8; ++s) {
        const int cur = s & 1;
#pragma unroll
        for (int mt = 0; mt < 2; ++mt)
#pragma unroll
          for (int nt = 0; nt < 2; ++nt)
            acc2[mt][nt] = MFMA(a2[cur][mt], b2r[cur][nt], acc2[mt][nt]);
      }
      __builtin_amdgcn_s_setprio(0);
    }
    // no trailing barrier: next chunk writes the other asb buffer
  }
#undef FF_LDA
#undef FF_LDB

  // ---- residual (h from bufA) + LN2 ----
  {
    float ps[2][4], ps2[2][4];
#pragma unroll
    for (int mt = 0; mt < 2; ++mt)
#pragma unroll
      for (int reg = 0; reg < 4; ++reg) {
        const int row = mt * 16 + q * 4 + reg;
        float s = 0.f, s2 = 0.f;
#pragma unroll
        for (int nt = 0; nt < 2; ++nt) {
          const int col = wv * 32 + nt * 16 + cl;
          const float y = acc2[mt][nt][reg] + bf2f(bufA[row * XPITCH + col]);
          acc2[mt][nt][reg] = y;
          s += y; s2 += y * y;
        }
#pragma unroll
        for (int off = 1; off < 16; off <<= 1) { s += __shfl_xor(s, off, 64); s2 += __shfl_xor(s2, off, 64); }
        ps[mt][reg] = s; ps2[mt][reg] = s2;
      }
    if (cl == 0) {
#pragma unroll
      for (int mt = 0; mt < 2; ++mt)
#pragma unroll
        for (int reg = 0; reg < 4; ++reg) {
          const int row = mt * 16 + q * 4 + reg;
          redS[wv][row] = ps[mt][reg]; redS2[wv][row] = ps2[mt][reg];
        }
    }
  }
  __syncthreads();
  if (tid < MT) {
    float s = 0.f, s2 = 0.f;
#pragma unroll
    for (int k = 0; k < 8; ++k) { s += redS[k][tid]; s2 += redS2[k][tid]; }
    const float mu = s * (1.f / DD);
    const float var = s2 * (1.f / DD) - mu * mu;
    muL[tid] = mu; invL[tid] = rsqrtf(var + EPSLN);
  }
  __syncthreads();

#pragma unroll
  for (int nt = 0; nt < 2; ++nt) {
    const int col = wv * 32 + nt * 16 + cl;
    const float gv = g2[col], bv = b2[col];
#pragma unroll
    for (int mt = 0; mt < 2; ++mt)
#pragma unroll
      for (int reg = 0; reg < 4; ++reg) {
        const int row = mt * 16 + q * 4 + reg;
        out[(tok0 + row) * DD + col] = (acc2[mt][nt][reg] - muL[row]) * invL[row] * gv + bv;
      }
  }
#undef bufB
}

// ---------------- launch ----------------
extern "C" void kernel_launch(void* const* d_in, const int* in_sizes, int n_in,
                              void* d_out, int out_size, void* d_ws, size_t ws_size,
                              hipStream_t stream) {
  const float* x    = (const float*)d_in[0];
  const float* wmix = (const float*)d_in[1];   // [3840][256]
  const float* bmix = (const float*)d_in[2];
  const float* g1   = (const float*)d_in[3];
  const float* b1   = (const float*)d_in[4];
  const float* wff1 = (const float*)d_in[5];   // [256][1024]
  const float* bff1 = (const float*)d_in[6];
  const float* wff2 = (const float*)d_in[7];   // [1024][256]
  const float* bff2 = (const float*)d_in[8];
  const float* g2   = (const float*)d_in[9];
  const float* b2   = (const float*)d_in[10];
  float* out = (float*)d_out;

  u16* wpk  = (u16*)d_ws;                // 120*8192 = 983040 elems (1.97 MB)
  u16* w1pk = wpk + 983040;              // 32*8192 = 262144
  u16* w2pk = w1pk + 262144;             // 262144

  // 184 slabs x 1024 fragments-of-8 = 188416 threads = 736 x 256
  k_prep<<<736, 256, 0, stream>>>(wmix, wff1, wff2, wpk, w1pk, w2pk);

  k_fused<<<512, 512, 0, stream>>>(x, wpk, bmix, g1, b1,
                                   w1pk, bff1, w2pk, bff2, g2, b2, out);
}